// Round 8
// baseline (162.178 us; speedup 1.0000x reference)
//
#include <hip/hip_runtime.h>

#define NCH 64
#define LAG 5
#define H0 32
#define H1 32
#define TIN 2048
#define TOUT 2044
#define NBATCH 16

#define XSTRIDE 72   // ushorts per staged X row (144 B, 16B-aligned rows)

typedef __attribute__((ext_vector_type(8))) short short8;    // 8 bf16 (4 VGPRs)
typedef __attribute__((ext_vector_type(4))) short short4v;   // 4 bf16 (2 VGPRs)
typedef __attribute__((ext_vector_type(4))) float f32x4;

__device__ __forceinline__ unsigned short f2bf(float f) {
    unsigned u = __float_as_uint(f);
    u += 0x7fffu + ((u >> 16) & 1u);     // RNE
    return (unsigned short)(u >> 16);
}

__device__ __forceinline__ unsigned pack2bf(float a, float b) {
    unsigned ua = __float_as_uint(a);
    unsigned ub = __float_as_uint(b);
    ua += 0x7fffu + ((ua >> 16) & 1u);
    ub += 0x7fffu + ((ub >> 16) & 1u);
    return (ua >> 16) | (ub & 0xffff0000u);
}

__device__ __forceinline__ unsigned pack2bf_relu(float a, float b) {
    return pack2bf(fmaxf(a, 0.0f), fmaxf(b, 0.0f));
}

__device__ __forceinline__ short4v pack4bf_relu(const f32x4& v) {
    union { short4v s; unsigned u[2]; } cv;
    cv.u[0] = pack2bf_relu(v[0], v[1]);
    cv.u[1] = pack2bf_relu(v[2], v[3]);
    return cv.s;
}

// ---- SINGLE DISPATCH: block = 256-pos tile x 4 nets; wave = net ----
// Weights converted fp32->bf16 in-register per wave (no prep kernels, no ws).
// Layer 0 transposed: D = W0(A-op) x Xwin^T(B-op) -> C[row=h][col=pos]; C is
// directly a B-operand of mfma_16x16x16bf16_1k, so layers 1-2 are register-only.
// blockIdx.x in [0,128): b = x>>3, t0 = (x&7)*256.  blockIdx.y in [0,16).
__global__ __launch_bounds__(256, 2) void mlp_mfma(
    const float* __restrict__ X,
    const float* __restrict__ W0, const float* __restrict__ b0,
    const float* __restrict__ W1, const float* __restrict__ b1,
    const float* __restrict__ W2, const float* __restrict__ b2,
    float* __restrict__ out)
{
    __shared__ __align__(16) unsigned short xs[260 * XSTRIDE];   // 37,440 B
    __shared__ __align__(16) float yt[256][4];                   //  4,096 B

    const int tileid = blockIdx.x;
    const int ng     = blockIdx.y;
    const int b      = tileid >> 3;
    const int t0     = (tileid & 7) * 256;
    const int tid    = threadIdx.x;
    const int wave   = tid >> 6;
    const int lane   = tid & 63;
    const int quad   = lane >> 4;
    const int l15    = lane & 15;

    // ---- stage X tile: fp32 -> bf16 -> LDS ----
    const float* src = X + ((size_t)(b * TIN + t0)) * NCH;
    const int rows = (t0 == 1792) ? 256 : 260;
    for (int s = tid; s < rows * 16; s += 256) {
        int r = s >> 4, seg = s & 15;
        float4 x = *(const float4*)(src + s * 4);
        unsigned long long v = (unsigned long long)f2bf(x.x)
                             | ((unsigned long long)f2bf(x.y) << 16)
                             | ((unsigned long long)f2bf(x.z) << 32)
                             | ((unsigned long long)f2bf(x.w) << 48);
        *(unsigned long long*)&xs[r * XSTRIDE + seg * 4] = v;
    }
    __syncthreads();

    // ---- per-wave net: weight fragments from fp32 globals, converted in-reg ----
    const int n = ng * 4 + wave;

    // W0 A-operand frags: row h = nf*16+l15, k = ks*32 + quad*8 + j
    // k = l*64 + c  ->  l = k>>6 = ks>>1, c = (ks&1)*32 + quad*8 + j (contiguous)
    // src W0[n][h][c][l]: stride over c is LAG floats.
    short8 B0[10][2];
    #pragma unroll
    for (int ks = 0; ks < 10; ++ks) {
        const int l     = ks >> 1;
        const int cbase = (ks & 1) * 32 + quad * 8;
        #pragma unroll
        for (int nf = 0; nf < 2; ++nf) {
            const int h = nf * 16 + l15;
            const float* p = W0 + ((size_t)(n * H0 + h) * NCH + cbase) * LAG + l;
            union { short8 s; unsigned u[4]; } cv;
            #pragma unroll
            for (int jj = 0; jj < 4; ++jj)
                cv.u[jj] = pack2bf(p[(2 * jj) * LAG], p[(2 * jj + 1) * LAG]);
            B0[ks][nf] = cv.s;
        }
    }
    // W1 A-operand: m = o = of*16+l15, k = i = kf*16 + quad*4 + j  (float4 loads)
    short4v A1[2][2];
    #pragma unroll
    for (int of = 0; of < 2; ++of)
        #pragma unroll
        for (int kf = 0; kf < 2; ++kf) {
            float4 w = *(const float4*)(W1 + (size_t)(n * H1 + of * 16 + l15) * H0 + kf * 16 + quad * 4);
            union { short4v s; unsigned u[2]; } cv;
            cv.u[0] = pack2bf(w.x, w.y);
            cv.u[1] = pack2bf(w.z, w.w);
            A1[of][kf] = cv.s;
        }
    // W2 A-operand (broadcast over m): k = o = kf*16 + quad*4 + j
    short4v A2[2];
    #pragma unroll
    for (int kf = 0; kf < 2; ++kf) {
        float4 w = *(const float4*)(W2 + (size_t)n * H1 + kf * 16 + quad * 4);
        union { short4v s; unsigned u[2]; } cv;
        cv.u[0] = pack2bf(w.x, w.y);
        cv.u[1] = pack2bf(w.z, w.w);
        A2[kf] = cv.s;
    }
    // biases: C rows are features -> per (quad,reg) float4 loads
    f32x4 b0q[2], b1q[2];
    #pragma unroll
    for (int nf = 0; nf < 2; ++nf) b0q[nf] = *(const f32x4*)(b0 + (size_t)n * H0 + nf * 16 + quad * 4);
    #pragma unroll
    for (int of = 0; of < 2; ++of) b1q[of] = *(const f32x4*)(b1 + (size_t)n * H1 + of * 16 + quad * 4);
    const float b2s = b2[n];

    const int vmax = (t0 == 1792) ? 251 : 255;

    #pragma unroll 1
    for (int chunk = 0; chunk < 4; ++chunk) {
        int rowoff[4];
        #pragma unroll
        for (int mf = 0; mf < 4; ++mf) {
            int i = chunk * 64 + mf * 16 + l15;
            i = i < vmax ? i : vmax;
            rowoff[mf] = i * XSTRIDE + quad * 8;
        }

        // ---- layer 0 (transposed): acc[mf][nf] = C[row=h][col=pos] ----
        f32x4 acc[4][2];
        #pragma unroll
        for (int mf = 0; mf < 4; ++mf) {
            acc[mf][0] = b0q[0];
            acc[mf][1] = b0q[1];
        }
        #pragma unroll
        for (int ks = 0; ks < 10; ++ks) {
            const int xoff = (ks >> 1) * XSTRIDE + (ks & 1) * 32;
            #pragma unroll
            for (int mf = 0; mf < 4; ++mf) {
                short8 Xf = *(const short8*)&xs[rowoff[mf] + xoff];   // B-op: n=pos
                acc[mf][0] = __builtin_amdgcn_mfma_f32_16x16x32_bf16(B0[ks][0], Xf, acc[mf][0], 0, 0, 0);
                acc[mf][1] = __builtin_amdgcn_mfma_f32_16x16x32_bf16(B0[ks][1], Xf, acc[mf][1], 0, 0, 0);
            }
        }

        // ---- layers 1+2: register-only ----
        #pragma unroll
        for (int mf = 0; mf < 4; ++mf) {
            short4v Bh0 = pack4bf_relu(acc[mf][0]);   // h 0..15
            short4v Bh1 = pack4bf_relu(acc[mf][1]);   // h 16..31

            f32x4 D1[2] = { b1q[0], b1q[1] };
            D1[0] = __builtin_amdgcn_mfma_f32_16x16x16bf16_1k(A1[0][0], Bh0, D1[0], 0, 0, 0);
            D1[0] = __builtin_amdgcn_mfma_f32_16x16x16bf16_1k(A1[0][1], Bh1, D1[0], 0, 0, 0);
            D1[1] = __builtin_amdgcn_mfma_f32_16x16x16bf16_1k(A1[1][0], Bh0, D1[1], 0, 0, 0);
            D1[1] = __builtin_amdgcn_mfma_f32_16x16x16bf16_1k(A1[1][1], Bh1, D1[1], 0, 0, 0);

            short4v Bg0 = pack4bf_relu(D1[0]);        // o 0..15
            short4v Bg1 = pack4bf_relu(D1[1]);        // o 16..31

            f32x4 D2 = (f32x4){ b2s, b2s, b2s, b2s };
            D2 = __builtin_amdgcn_mfma_f32_16x16x16bf16_1k(A2[0], Bg0, D2, 0, 0, 0);
            D2 = __builtin_amdgcn_mfma_f32_16x16x16bf16_1k(A2[1], Bg1, D2, 0, 0, 0);

            if (quad == 0)
                yt[chunk * 64 + mf * 16 + l15][wave] = D2[0];
        }
    }
    __syncthreads();

    // ---- coalesced output: float4 per thread ----
    int t = t0 + tid;
    if (t < TOUT) {
        float4 v = *(const float4*)yt[tid];
        *(float4*)&out[((size_t)(b * TOUT + t)) * NCH + ng * 4] = v;
    }
}

extern "C" void kernel_launch(void* const* d_in, const int* in_sizes, int n_in,
                              void* d_out, int out_size, void* d_ws, size_t ws_size,
                              hipStream_t stream)
{
    const float* X  = (const float*)d_in[0];
    const float* W0 = (const float*)d_in[1];
    const float* b0 = (const float*)d_in[2];
    const float* W1 = (const float*)d_in[3];
    const float* b1 = (const float*)d_in[4];
    const float* W2 = (const float*)d_in[5];
    const float* b2 = (const float*)d_in[6];
    float* out = (float*)d_out;

    mlp_mfma<<<dim3(128, 16), 256, 0, stream>>>(X, W0, b0, W1, b1, W2, b2, out);
}

// Round 9
// 152.210 us; speedup vs baseline: 1.0655x; 1.0655x over previous
//
#include <hip/hip_runtime.h>

#define NCH 64
#define LAG 5
#define H0 32
#define H1 32
#define TIN 2048
#define TOUT 2044
#define NBATCH 16

// xs: 260 rows x 64 ushorts (128 B). 16-B chunk c of row r stored at chunk
// slot (c ^ (r & 7)) -> bank-conflict-free reads AND writes, no padding.

typedef __attribute__((ext_vector_type(8))) short short8;    // 8 bf16 (4 VGPRs)
typedef __attribute__((ext_vector_type(4))) short short4v;   // 4 bf16 (2 VGPRs)
typedef __attribute__((ext_vector_type(4))) float f32x4;

__device__ __forceinline__ unsigned short f2bf(float f) {
    unsigned u = __float_as_uint(f);
    u += 0x7fffu + ((u >> 16) & 1u);     // RNE
    return (unsigned short)(u >> 16);
}

__device__ __forceinline__ unsigned pack2bf_relu(float a, float b) {
    unsigned ua = __float_as_uint(fmaxf(a, 0.0f));
    unsigned ub = __float_as_uint(fmaxf(b, 0.0f));
    ua += 0x7fffu + ((ua >> 16) & 1u);
    ub += 0x7fffu + ((ub >> 16) & 1u);
    return (ua >> 16) | (ub & 0xffff0000u);
}

__device__ __forceinline__ short4v pack4bf_relu(const f32x4& v) {
    union { short4v s; unsigned u[2]; } cv;
    cv.u[0] = pack2bf_relu(v[0], v[1]);
    cv.u[1] = pack2bf_relu(v[2], v[3]);
    return cv.s;
}

// ---- weights-only prep (R7 structure) ----
__global__ __launch_bounds__(256) void prep_w(
    const float* __restrict__ W0, unsigned short* __restrict__ W0b,
    const float* __restrict__ W1, unsigned short* __restrict__ W1b,
    const float* __restrict__ W2, unsigned short* __restrict__ W2b)
{
    const int bx = blockIdx.x;
    if (bx < 512) {
        int j = bx * 256 + threadIdx.x;            // 131072 = 64n * 32h * 64c
        int nh = j >> 6, c = j & 63;
        const float* src = W0 + (size_t)j * LAG;
        unsigned short* dst = W0b + nh * 320 + c;
        #pragma unroll
        for (int l = 0; l < LAG; ++l) dst[l * 64] = f2bf(src[l]);
    } else if (bx < 544) {
        int i = ((bx - 512) * 256 + threadIdx.x) * 8;
        float4 a = *(const float4*)(W1 + i);
        float4 b = *(const float4*)(W1 + i + 4);
        unsigned long long v0 = (unsigned long long)f2bf(a.x)
                              | ((unsigned long long)f2bf(a.y) << 16)
                              | ((unsigned long long)f2bf(a.z) << 32)
                              | ((unsigned long long)f2bf(a.w) << 48);
        unsigned long long v1 = (unsigned long long)f2bf(b.x)
                              | ((unsigned long long)f2bf(b.y) << 16)
                              | ((unsigned long long)f2bf(b.z) << 32)
                              | ((unsigned long long)f2bf(b.w) << 48);
        *(unsigned long long*)(W1b + i)     = v0;
        *(unsigned long long*)(W1b + i + 4) = v1;
    } else {
        int i = threadIdx.x * 8;
        float4 a = *(const float4*)(W2 + i);
        float4 b = *(const float4*)(W2 + i + 4);
        unsigned long long v0 = (unsigned long long)f2bf(a.x)
                              | ((unsigned long long)f2bf(a.y) << 16)
                              | ((unsigned long long)f2bf(a.z) << 32)
                              | ((unsigned long long)f2bf(a.w) << 48);
        unsigned long long v1 = (unsigned long long)f2bf(b.x)
                              | ((unsigned long long)f2bf(b.y) << 16)
                              | ((unsigned long long)f2bf(b.z) << 32)
                              | ((unsigned long long)f2bf(b.w) << 48);
        *(unsigned long long*)(W2b + i)     = v0;
        *(unsigned long long*)(W2b + i + 4) = v1;
    }
}

// ---- main: block = 256-pos tile x 4 nets; wave = net; register-only L1/L2 ----
// Layer 0 transposed: D = W0(A-op) x Xwin^T(B-op) -> C[row=h][col=pos].
// LDS: swizzled xs (33,280 B) + yt (4,096 B) = 37,376 B < 40,960 -> 3 blocks/CU.
__global__ __launch_bounds__(256, 3) void mlp_mfma(
    const float* __restrict__ X,
    const unsigned short* __restrict__ W0b,
    const unsigned short* __restrict__ W1b,
    const unsigned short* __restrict__ W2b,
    const float* __restrict__ b0, const float* __restrict__ b1,
    const float* __restrict__ b2, float* __restrict__ out)
{
    __shared__ __align__(16) unsigned short xs[260 * 64];   // 33,280 B, swizzled
    __shared__ __align__(16) float yt[256][4];              //  4,096 B

    const int tileid = blockIdx.x;
    const int ng     = blockIdx.y;
    const int b      = tileid >> 3;
    const int t0     = (tileid & 7) * 256;
    const int tid    = threadIdx.x;
    const int wave   = tid >> 6;
    const int lane   = tid & 63;
    const int quad   = lane >> 4;
    const int l15    = lane & 15;

    // ---- stage X tile: fp32 -> bf16 -> swizzled LDS ----
    const float* src = X + ((size_t)(b * TIN + t0)) * NCH;
    const int rows = (t0 == 1792) ? 256 : 260;
    for (int s = tid; s < rows * 16; s += 256) {
        int r = s >> 4, seg = s & 15;
        float4 x = *(const float4*)(src + s * 4);
        unsigned long long v = (unsigned long long)f2bf(x.x)
                             | ((unsigned long long)f2bf(x.y) << 16)
                             | ((unsigned long long)f2bf(x.z) << 32)
                             | ((unsigned long long)f2bf(x.w) << 48);
        int c = seg >> 1, h = seg & 1;
        *(unsigned long long*)&xs[r * 64 + (((c ^ (r & 7)) << 3) | (h << 2))] = v;
    }
    __syncthreads();

    // ---- per-wave net: weight fragments (pre-repacked bf16), loaded once ----
    const int n = ng * 4 + wave;
    short8 B0[10][2];
    const unsigned short* wp0 = W0b + (n * H0 + l15) * (NCH * LAG) + quad * 8;
    #pragma unroll
    for (int ks = 0; ks < 10; ++ks) {
        B0[ks][0] = *(const short8*)(wp0 + ks * 32);
        B0[ks][1] = *(const short8*)(wp0 + 16 * (NCH * LAG) + ks * 32);
    }
    short4v A1[2][2];
    #pragma unroll
    for (int of = 0; of < 2; ++of)
        #pragma unroll
        for (int kf = 0; kf < 2; ++kf)
            A1[of][kf] = *(const short4v*)(W1b + (n * H1 + of * 16 + l15) * H0 + kf * 16 + quad * 4);
    short4v A2[2];
    #pragma unroll
    for (int kf = 0; kf < 2; ++kf)
        A2[kf] = *(const short4v*)(W2b + n * H1 + kf * 16 + quad * 4);
    f32x4 b0q[2], b1q[2];
    #pragma unroll
    for (int nf = 0; nf < 2; ++nf) b0q[nf] = *(const f32x4*)(b0 + (size_t)n * H0 + nf * 16 + quad * 4);
    #pragma unroll
    for (int of = 0; of < 2; ++of) b1q[of] = *(const f32x4*)(b1 + (size_t)n * H1 + of * 16 + quad * 4);
    const float b2s = b2[n];

    const int vmax = (t0 == 1792) ? 251 : 255;
    const int cq[2] = { quad, quad + 4 };   // in-row chunk for ks parity 0/1

    #pragma unroll 1
    for (int chunk = 0; chunk < 4; ++chunk) {
        int i64[4], i7[4];
        #pragma unroll
        for (int mf = 0; mf < 4; ++mf) {
            int i = chunk * 64 + mf * 16 + l15;
            i = i < vmax ? i : vmax;
            i64[mf] = i * 64;
            i7[mf]  = i & 7;
        }

        // ---- layer 0 (transposed): acc[mf][nf] = C[row=h][col=pos] ----
        f32x4 acc[4][2];
        #pragma unroll
        for (int mf = 0; mf < 4; ++mf) {
            acc[mf][0] = b0q[0];
            acc[mf][1] = b0q[1];
        }
        #pragma unroll
        for (int ks = 0; ks < 10; ++ks) {
            const int l = ks >> 1;
            const int p = ks & 1;
            #pragma unroll
            for (int mf = 0; mf < 4; ++mf) {
                int sw = (cq[p] ^ ((i7[mf] + l) & 7)) << 3;
                short8 Xf = *(const short8*)&xs[i64[mf] + l * 64 + sw];
                acc[mf][0] = __builtin_amdgcn_mfma_f32_16x16x32_bf16(B0[ks][0], Xf, acc[mf][0], 0, 0, 0);
                acc[mf][1] = __builtin_amdgcn_mfma_f32_16x16x32_bf16(B0[ks][1], Xf, acc[mf][1], 0, 0, 0);
            }
        }

        // ---- layers 1+2: register-only ----
        #pragma unroll
        for (int mf = 0; mf < 4; ++mf) {
            short4v Bh0 = pack4bf_relu(acc[mf][0]);   // h 0..15
            short4v Bh1 = pack4bf_relu(acc[mf][1]);   // h 16..31

            f32x4 D1[2] = { b1q[0], b1q[1] };
            D1[0] = __builtin_amdgcn_mfma_f32_16x16x16bf16_1k(A1[0][0], Bh0, D1[0], 0, 0, 0);
            D1[0] = __builtin_amdgcn_mfma_f32_16x16x16bf16_1k(A1[0][1], Bh1, D1[0], 0, 0, 0);
            D1[1] = __builtin_amdgcn_mfma_f32_16x16x16bf16_1k(A1[1][0], Bh0, D1[1], 0, 0, 0);
            D1[1] = __builtin_amdgcn_mfma_f32_16x16x16bf16_1k(A1[1][1], Bh1, D1[1], 0, 0, 0);

            short4v Bg0 = pack4bf_relu(D1[0]);        // o 0..15
            short4v Bg1 = pack4bf_relu(D1[1]);        // o 16..31

            f32x4 D2 = (f32x4){ b2s, b2s, b2s, b2s };
            D2 = __builtin_amdgcn_mfma_f32_16x16x16bf16_1k(A2[0], Bg0, D2, 0, 0, 0);
            D2 = __builtin_amdgcn_mfma_f32_16x16x16bf16_1k(A2[1], Bg1, D2, 0, 0, 0);

            if (quad == 0)
                yt[chunk * 64 + mf * 16 + l15][wave] = D2[0];
        }
    }
    __syncthreads();

    // ---- coalesced output: float4 per thread ----
    int t = t0 + tid;
    if (t < TOUT) {
        float4 v = *(const float4*)yt[tid];
        *(float4*)&out[((size_t)(b * TOUT + t)) * NCH + ng * 4] = v;
    }
}

extern "C" void kernel_launch(void* const* d_in, const int* in_sizes, int n_in,
                              void* d_out, int out_size, void* d_ws, size_t ws_size,
                              hipStream_t stream)
{
    const float* X  = (const float*)d_in[0];
    const float* W0 = (const float*)d_in[1];
    const float* b0 = (const float*)d_in[2];
    const float* W1 = (const float*)d_in[3];
    const float* b1 = (const float*)d_in[4];
    const float* W2 = (const float*)d_in[5];
    const float* b2 = (const float*)d_in[6];
    float* out = (float*)d_out;

    unsigned short* W0b = (unsigned short*)d_ws;                    // 1,310,720 B
    unsigned short* W1b = (unsigned short*)((char*)d_ws + 1310720); //   131,072 B
    unsigned short* W2b = (unsigned short*)((char*)d_ws + 1441792); //     4,096 B

    prep_w<<<545, 256, 0, stream>>>(W0, W0b, W1, W1b, W2, W2b);
    mlp_mfma<<<dim3(128, 16), 256, 0, stream>>>(X, W0b, W1b, W2b, b0, b1, b2, out);
}

// Round 10
// 131.964 us; speedup vs baseline: 1.2290x; 1.1534x over previous
//
#include <hip/hip_runtime.h>

#define NCH 64
#define LAG 5
#define H0 32
#define H1 32
#define TIN 2048
#define TOUT 2044
#define NBATCH 16

// xs: 260 rows x 64 ushorts (128 B). 16-B chunk c of row r stored at chunk
// slot (c ^ (r & 7)) -> bank-conflict-free reads AND writes, no padding.

typedef __attribute__((ext_vector_type(8))) short short8;    // 8 bf16 (4 VGPRs)
typedef __attribute__((ext_vector_type(4))) short short4v;   // 4 bf16 (2 VGPRs)
typedef __attribute__((ext_vector_type(4))) float f32x4;

__device__ __forceinline__ unsigned short f2bf(float f) {
    unsigned u = __float_as_uint(f);
    u += 0x7fffu + ((u >> 16) & 1u);     // RNE
    return (unsigned short)(u >> 16);
}

__device__ __forceinline__ unsigned pack2bf_relu(float a, float b) {
    unsigned ua = __float_as_uint(fmaxf(a, 0.0f));
    unsigned ub = __float_as_uint(fmaxf(b, 0.0f));
    ua += 0x7fffu + ((ua >> 16) & 1u);
    ub += 0x7fffu + ((ub >> 16) & 1u);
    return (ua >> 16) | (ub & 0xffff0000u);
}

__device__ __forceinline__ short4v pack4bf_relu(const f32x4& v) {
    union { short4v s; unsigned u[2]; } cv;
    cv.u[0] = pack2bf_relu(v[0], v[1]);
    cv.u[1] = pack2bf_relu(v[2], v[3]);
    return cv.s;
}

// ---- weights-only prep ----
__global__ __launch_bounds__(256) void prep_w(
    const float* __restrict__ W0, unsigned short* __restrict__ W0b,
    const float* __restrict__ W1, unsigned short* __restrict__ W1b,
    const float* __restrict__ W2, unsigned short* __restrict__ W2b)
{
    const int bx = blockIdx.x;
    if (bx < 512) {
        int j = bx * 256 + threadIdx.x;            // 131072 = 64n * 32h * 64c
        int nh = j >> 6, c = j & 63;
        const float* src = W0 + (size_t)j * LAG;
        unsigned short* dst = W0b + nh * 320 + c;
        #pragma unroll
        for (int l = 0; l < LAG; ++l) dst[l * 64] = f2bf(src[l]);
    } else if (bx < 544) {
        int i = ((bx - 512) * 256 + threadIdx.x) * 8;
        float4 a = *(const float4*)(W1 + i);
        float4 b = *(const float4*)(W1 + i + 4);
        unsigned long long v0 = (unsigned long long)f2bf(a.x)
                              | ((unsigned long long)f2bf(a.y) << 16)
                              | ((unsigned long long)f2bf(a.z) << 32)
                              | ((unsigned long long)f2bf(a.w) << 48);
        unsigned long long v1 = (unsigned long long)f2bf(b.x)
                              | ((unsigned long long)f2bf(b.y) << 16)
                              | ((unsigned long long)f2bf(b.z) << 32)
                              | ((unsigned long long)f2bf(b.w) << 48);
        *(unsigned long long*)(W1b + i)     = v0;
        *(unsigned long long*)(W1b + i + 4) = v1;
    } else {
        int i = threadIdx.x * 8;
        float4 a = *(const float4*)(W2 + i);
        float4 b = *(const float4*)(W2 + i + 4);
        unsigned long long v0 = (unsigned long long)f2bf(a.x)
                              | ((unsigned long long)f2bf(a.y) << 16)
                              | ((unsigned long long)f2bf(a.z) << 32)
                              | ((unsigned long long)f2bf(a.w) << 48);
        unsigned long long v1 = (unsigned long long)f2bf(b.x)
                              | ((unsigned long long)f2bf(b.y) << 16)
                              | ((unsigned long long)f2bf(b.z) << 32)
                              | ((unsigned long long)f2bf(b.w) << 48);
        *(unsigned long long*)(W2b + i)     = v0;
        *(unsigned long long*)(W2b + i + 4) = v1;
    }
}

// ---- main: block = 256-pos tile x 4 nets; wave = net; register-only L1/L2 ----
// Layer 0 transposed: D = W0(A-op) x Xwin^T(B-op) -> C[row=h][col=pos].
// Swizzled xs => zero bank conflicts; launch_bounds (256,2) => no spill (R9 lesson).
__global__ __launch_bounds__(256, 2) void mlp_mfma(
    const float* __restrict__ X,
    const unsigned short* __restrict__ W0b,
    const unsigned short* __restrict__ W1b,
    const unsigned short* __restrict__ W2b,
    const float* __restrict__ b0, const float* __restrict__ b1,
    const float* __restrict__ b2, float* __restrict__ out)
{
    __shared__ __align__(16) unsigned short xs[260 * 64];   // 33,280 B, swizzled
    __shared__ __align__(16) float yt[256][4];              //  4,096 B

    const int tileid = blockIdx.x;
    const int ng     = blockIdx.y;
    const int b      = tileid >> 3;
    const int t0     = (tileid & 7) * 256;
    const int tid    = threadIdx.x;
    const int wave   = tid >> 6;
    const int lane   = tid & 63;
    const int quad   = lane >> 4;
    const int l15    = lane & 15;

    // ---- stage X tile: fp32 -> bf16 -> swizzled LDS ----
    const float* src = X + ((size_t)(b * TIN + t0)) * NCH;
    const int rows = (t0 == 1792) ? 256 : 260;
    for (int s = tid; s < rows * 16; s += 256) {
        int r = s >> 4, seg = s & 15;
        float4 x = *(const float4*)(src + s * 4);
        unsigned long long v = (unsigned long long)f2bf(x.x)
                             | ((unsigned long long)f2bf(x.y) << 16)
                             | ((unsigned long long)f2bf(x.z) << 32)
                             | ((unsigned long long)f2bf(x.w) << 48);
        int c = seg >> 1, h = seg & 1;
        *(unsigned long long*)&xs[r * 64 + (((c ^ (r & 7)) << 3) | (h << 2))] = v;
    }
    __syncthreads();

    // ---- per-wave net: weight fragments (pre-repacked bf16), loaded once ----
    const int n = ng * 4 + wave;
    short8 B0[10][2];
    const unsigned short* wp0 = W0b + (n * H0 + l15) * (NCH * LAG) + quad * 8;
    #pragma unroll
    for (int ks = 0; ks < 10; ++ks) {
        B0[ks][0] = *(const short8*)(wp0 + ks * 32);
        B0[ks][1] = *(const short8*)(wp0 + 16 * (NCH * LAG) + ks * 32);
    }
    short4v A1[2][2];
    #pragma unroll
    for (int of = 0; of < 2; ++of)
        #pragma unroll
        for (int kf = 0; kf < 2; ++kf)
            A1[of][kf] = *(const short4v*)(W1b + (n * H1 + of * 16 + l15) * H0 + kf * 16 + quad * 4);
    short4v A2[2];
    #pragma unroll
    for (int kf = 0; kf < 2; ++kf)
        A2[kf] = *(const short4v*)(W2b + n * H1 + kf * 16 + quad * 4);
    f32x4 b0q[2], b1q[2];
    #pragma unroll
    for (int nf = 0; nf < 2; ++nf) b0q[nf] = *(const f32x4*)(b0 + (size_t)n * H0 + nf * 16 + quad * 4);
    #pragma unroll
    for (int of = 0; of < 2; ++of) b1q[of] = *(const f32x4*)(b1 + (size_t)n * H1 + of * 16 + quad * 4);
    const float b2s = b2[n];

    const int vmax = (t0 == 1792) ? 251 : 255;
    const int cq[2] = { quad, quad + 4 };   // in-row chunk for ks parity 0/1

    #pragma unroll 1
    for (int chunk = 0; chunk < 4; ++chunk) {
        int i64[4], i7[4];
        #pragma unroll
        for (int mf = 0; mf < 4; ++mf) {
            int i = chunk * 64 + mf * 16 + l15;
            i = i < vmax ? i : vmax;
            i64[mf] = i * 64;
            i7[mf]  = i & 7;
        }

        // ---- layer 0 (transposed): acc[mf][nf] = C[row=h][col=pos] ----
        f32x4 acc[4][2];
        #pragma unroll
        for (int mf = 0; mf < 4; ++mf) {
            acc[mf][0] = b0q[0];
            acc[mf][1] = b0q[1];
        }
        #pragma unroll
        for (int ks = 0; ks < 10; ++ks) {
            const int l = ks >> 1;
            const int p = ks & 1;
            #pragma unroll
            for (int mf = 0; mf < 4; ++mf) {
                int sw = (cq[p] ^ ((i7[mf] + l) & 7)) << 3;
                short8 Xf = *(const short8*)&xs[i64[mf] + l * 64 + sw];
                acc[mf][0] = __builtin_amdgcn_mfma_f32_16x16x32_bf16(B0[ks][0], Xf, acc[mf][0], 0, 0, 0);
                acc[mf][1] = __builtin_amdgcn_mfma_f32_16x16x32_bf16(B0[ks][1], Xf, acc[mf][1], 0, 0, 0);
            }
        }

        // ---- layers 1+2: register-only ----
        #pragma unroll
        for (int mf = 0; mf < 4; ++mf) {
            short4v Bh0 = pack4bf_relu(acc[mf][0]);   // h 0..15
            short4v Bh1 = pack4bf_relu(acc[mf][1]);   // h 16..31

            f32x4 D1[2] = { b1q[0], b1q[1] };
            D1[0] = __builtin_amdgcn_mfma_f32_16x16x16bf16_1k(A1[0][0], Bh0, D1[0], 0, 0, 0);
            D1[0] = __builtin_amdgcn_mfma_f32_16x16x16bf16_1k(A1[0][1], Bh1, D1[0], 0, 0, 0);
            D1[1] = __builtin_amdgcn_mfma_f32_16x16x16bf16_1k(A1[1][0], Bh0, D1[1], 0, 0, 0);
            D1[1] = __builtin_amdgcn_mfma_f32_16x16x16bf16_1k(A1[1][1], Bh1, D1[1], 0, 0, 0);

            short4v Bg0 = pack4bf_relu(D1[0]);        // o 0..15
            short4v Bg1 = pack4bf_relu(D1[1]);        // o 16..31

            f32x4 D2 = (f32x4){ b2s, b2s, b2s, b2s };
            D2 = __builtin_amdgcn_mfma_f32_16x16x16bf16_1k(A2[0], Bg0, D2, 0, 0, 0);
            D2 = __builtin_amdgcn_mfma_f32_16x16x16bf16_1k(A2[1], Bg1, D2, 0, 0, 0);

            if (quad == 0)
                yt[chunk * 64 + mf * 16 + l15][wave] = D2[0];
        }
    }
    __syncthreads();

    // ---- coalesced output: float4 per thread ----
    int t = t0 + tid;
    if (t < TOUT) {
        float4 v = *(const float4*)yt[tid];
        *(float4*)&out[((size_t)(b * TOUT + t)) * NCH + ng * 4] = v;
    }
}

extern "C" void kernel_launch(void* const* d_in, const int* in_sizes, int n_in,
                              void* d_out, int out_size, void* d_ws, size_t ws_size,
                              hipStream_t stream)
{
    const float* X  = (const float*)d_in[0];
    const float* W0 = (const float*)d_in[1];
    const float* b0 = (const float*)d_in[2];
    const float* W1 = (const float*)d_in[3];
    const float* b1 = (const float*)d_in[4];
    const float* W2 = (const float*)d_in[5];
    const float* b2 = (const float*)d_in[6];
    float* out = (float*)d_out;

    unsigned short* W0b = (unsigned short*)d_ws;                    // 1,310,720 B
    unsigned short* W1b = (unsigned short*)((char*)d_ws + 1310720); //   131,072 B
    unsigned short* W2b = (unsigned short*)((char*)d_ws + 1441792); //     4,096 B

    prep_w<<<545, 256, 0, stream>>>(W0, W0b, W1, W1b, W2, W2b);
    mlp_mfma<<<dim3(128, 16), 256, 0, stream>>>(X, W0b, W1b, W2b, b0, b1, b2, out);
}

// Round 11
// 124.678 us; speedup vs baseline: 1.3008x; 1.0584x over previous
//
#include <hip/hip_runtime.h>

#define NCH 64
#define LAG 5
#define H0 32
#define H1 32
#define TIN 2048
#define TOUT 2044
#define NBATCH 16

#define XSTRIDE 72   // ushorts per staged X row (144 B, 16B-aligned rows)

typedef __attribute__((ext_vector_type(8))) short short8;    // 8 bf16 (4 VGPRs)
typedef __attribute__((ext_vector_type(4))) short short4v;   // 4 bf16 (2 VGPRs)
typedef __attribute__((ext_vector_type(4))) float f32x4;

__device__ __forceinline__ unsigned short f2bf(float f) {
    unsigned u = __float_as_uint(f);
    u += 0x7fffu + ((u >> 16) & 1u);     // RNE
    return (unsigned short)(u >> 16);
}

__device__ __forceinline__ unsigned pack2bf_relu(float a, float b) {
    unsigned ua = __float_as_uint(fmaxf(a, 0.0f));
    unsigned ub = __float_as_uint(fmaxf(b, 0.0f));
    ua += 0x7fffu + ((ua >> 16) & 1u);
    ub += 0x7fffu + ((ub >> 16) & 1u);
    return (ua >> 16) | (ub & 0xffff0000u);
}

__device__ __forceinline__ short4v pack4bf_relu(const f32x4& v) {
    union { short4v s; unsigned u[2]; } cv;
    cv.u[0] = pack2bf_relu(v[0], v[1]);
    cv.u[1] = pack2bf_relu(v[2], v[3]);
    return cv.s;
}

// ---- weights-only prep ----
__global__ __launch_bounds__(256) void prep_w(
    const float* __restrict__ W0, unsigned short* __restrict__ W0b,
    const float* __restrict__ W1, unsigned short* __restrict__ W1b,
    const float* __restrict__ W2, unsigned short* __restrict__ W2b)
{
    const int bx = blockIdx.x;
    if (bx < 512) {
        int j = bx * 256 + threadIdx.x;            // 131072 = 64n * 32h * 64c
        int nh = j >> 6, c = j & 63;
        const float* src = W0 + (size_t)j * LAG;
        unsigned short* dst = W0b + nh * 320 + c;
        #pragma unroll
        for (int l = 0; l < LAG; ++l) dst[l * 64] = f2bf(src[l]);
    } else if (bx < 544) {
        int i = ((bx - 512) * 256 + threadIdx.x) * 8;
        float4 a = *(const float4*)(W1 + i);
        float4 b = *(const float4*)(W1 + i + 4);
        unsigned long long v0 = (unsigned long long)f2bf(a.x)
                              | ((unsigned long long)f2bf(a.y) << 16)
                              | ((unsigned long long)f2bf(a.z) << 32)
                              | ((unsigned long long)f2bf(a.w) << 48);
        unsigned long long v1 = (unsigned long long)f2bf(b.x)
                              | ((unsigned long long)f2bf(b.y) << 16)
                              | ((unsigned long long)f2bf(b.z) << 32)
                              | ((unsigned long long)f2bf(b.w) << 48);
        *(unsigned long long*)(W1b + i)     = v0;
        *(unsigned long long*)(W1b + i + 4) = v1;
    } else {
        int i = threadIdx.x * 8;
        float4 a = *(const float4*)(W2 + i);
        float4 b = *(const float4*)(W2 + i + 4);
        unsigned long long v0 = (unsigned long long)f2bf(a.x)
                              | ((unsigned long long)f2bf(a.y) << 16)
                              | ((unsigned long long)f2bf(a.z) << 32)
                              | ((unsigned long long)f2bf(a.w) << 48);
        unsigned long long v1 = (unsigned long long)f2bf(b.x)
                              | ((unsigned long long)f2bf(b.y) << 16)
                              | ((unsigned long long)f2bf(b.z) << 32)
                              | ((unsigned long long)f2bf(b.w) << 48);
        *(unsigned long long*)(W2b + i)     = v0;
        *(unsigned long long*)(W2b + i + 4) = v1;
    }
}

// ---- main: block = 256-pos tile x 4 nets; wave = net; register-only L1/L2 ----
// Layer 0 transposed: D = W0(A-op) x Xwin^T(B-op) -> C[row=h][col=pos].
// mf=2 / chunk=8: acc tile halved (16 AGPR) to fit 3 waves/SIMD at (256,3).
// R7 padded LDS layout: row-base VGPR + compile-time ds_read offsets.
__global__ __launch_bounds__(256, 3) void mlp_mfma(
    const float* __restrict__ X,
    const unsigned short* __restrict__ W0b,
    const unsigned short* __restrict__ W1b,
    const unsigned short* __restrict__ W2b,
    const float* __restrict__ b0, const float* __restrict__ b1,
    const float* __restrict__ b2, float* __restrict__ out)
{
    __shared__ __align__(16) unsigned short xs[260 * XSTRIDE];   // 37,440 B
    __shared__ __align__(16) float yt[256][4];                   //  4,096 B

    const int tileid = blockIdx.x;
    const int ng     = blockIdx.y;
    const int b      = tileid >> 3;
    const int t0     = (tileid & 7) * 256;
    const int tid    = threadIdx.x;
    const int wave   = tid >> 6;
    const int lane   = tid & 63;
    const int quad   = lane >> 4;
    const int l15    = lane & 15;

    // ---- stage X tile: fp32 -> bf16 -> LDS ----
    const float* src = X + ((size_t)(b * TIN + t0)) * NCH;
    const int rows = (t0 == 1792) ? 256 : 260;
    for (int s = tid; s < rows * 16; s += 256) {
        int r = s >> 4, seg = s & 15;
        float4 x = *(const float4*)(src + s * 4);
        unsigned long long v = (unsigned long long)f2bf(x.x)
                             | ((unsigned long long)f2bf(x.y) << 16)
                             | ((unsigned long long)f2bf(x.z) << 32)
                             | ((unsigned long long)f2bf(x.w) << 48);
        *(unsigned long long*)&xs[r * XSTRIDE + seg * 4] = v;
    }
    __syncthreads();

    // ---- per-wave net: weight fragments (pre-repacked bf16), loaded once ----
    const int n = ng * 4 + wave;
    short8 B0[10][2];
    const unsigned short* wp0 = W0b + (n * H0 + l15) * (NCH * LAG) + quad * 8;
    #pragma unroll
    for (int ks = 0; ks < 10; ++ks) {
        B0[ks][0] = *(const short8*)(wp0 + ks * 32);
        B0[ks][1] = *(const short8*)(wp0 + 16 * (NCH * LAG) + ks * 32);
    }
    short4v A1[2][2];
    #pragma unroll
    for (int of = 0; of < 2; ++of)
        #pragma unroll
        for (int kf = 0; kf < 2; ++kf)
            A1[of][kf] = *(const short4v*)(W1b + (n * H1 + of * 16 + l15) * H0 + kf * 16 + quad * 4);
    short4v A2[2];
    #pragma unroll
    for (int kf = 0; kf < 2; ++kf)
        A2[kf] = *(const short4v*)(W2b + n * H1 + kf * 16 + quad * 4);
    f32x4 b0q[2], b1q[2];
    #pragma unroll
    for (int nf = 0; nf < 2; ++nf) b0q[nf] = *(const f32x4*)(b0 + (size_t)n * H0 + nf * 16 + quad * 4);
    #pragma unroll
    for (int of = 0; of < 2; ++of) b1q[of] = *(const f32x4*)(b1 + (size_t)n * H1 + of * 16 + quad * 4);
    const float b2s = b2[n];

    const int vmax = (t0 == 1792) ? 251 : 255;

    #pragma unroll 1
    for (int chunk = 0; chunk < 8; ++chunk) {
        int rowoff[2];
        #pragma unroll
        for (int mf = 0; mf < 2; ++mf) {
            int i = chunk * 32 + mf * 16 + l15;
            i = i < vmax ? i : vmax;
            rowoff[mf] = i * XSTRIDE + quad * 8;
        }

        // ---- layer 0 (transposed): acc[mf][nf] = C[row=h][col=pos] ----
        f32x4 acc[2][2];
        #pragma unroll
        for (int mf = 0; mf < 2; ++mf) {
            acc[mf][0] = b0q[0];
            acc[mf][1] = b0q[1];
        }
        #pragma unroll
        for (int ks = 0; ks < 10; ++ks) {
            const int xoff = (ks >> 1) * XSTRIDE + (ks & 1) * 32;
            #pragma unroll
            for (int mf = 0; mf < 2; ++mf) {
                short8 Xf = *(const short8*)&xs[rowoff[mf] + xoff];   // B-op: n=pos
                acc[mf][0] = __builtin_amdgcn_mfma_f32_16x16x32_bf16(B0[ks][0], Xf, acc[mf][0], 0, 0, 0);
                acc[mf][1] = __builtin_amdgcn_mfma_f32_16x16x32_bf16(B0[ks][1], Xf, acc[mf][1], 0, 0, 0);
            }
        }

        // ---- layers 1+2: register-only ----
        #pragma unroll
        for (int mf = 0; mf < 2; ++mf) {
            short4v Bh0 = pack4bf_relu(acc[mf][0]);   // h 0..15
            short4v Bh1 = pack4bf_relu(acc[mf][1]);   // h 16..31

            f32x4 D1[2] = { b1q[0], b1q[1] };
            D1[0] = __builtin_amdgcn_mfma_f32_16x16x16bf16_1k(A1[0][0], Bh0, D1[0], 0, 0, 0);
            D1[0] = __builtin_amdgcn_mfma_f32_16x16x16bf16_1k(A1[0][1], Bh1, D1[0], 0, 0, 0);
            D1[1] = __builtin_amdgcn_mfma_f32_16x16x16bf16_1k(A1[1][0], Bh0, D1[1], 0, 0, 0);
            D1[1] = __builtin_amdgcn_mfma_f32_16x16x16bf16_1k(A1[1][1], Bh1, D1[1], 0, 0, 0);

            short4v Bg0 = pack4bf_relu(D1[0]);        // o 0..15
            short4v Bg1 = pack4bf_relu(D1[1]);        // o 16..31

            f32x4 D2 = (f32x4){ b2s, b2s, b2s, b2s };
            D2 = __builtin_amdgcn_mfma_f32_16x16x16bf16_1k(A2[0], Bg0, D2, 0, 0, 0);
            D2 = __builtin_amdgcn_mfma_f32_16x16x16bf16_1k(A2[1], Bg1, D2, 0, 0, 0);

            if (quad == 0)
                yt[chunk * 32 + mf * 16 + l15][wave] = D2[0];
        }
    }
    __syncthreads();

    // ---- coalesced output: float4 per thread ----
    int t = t0 + tid;
    if (t < TOUT) {
        float4 v = *(const float4*)yt[tid];
        *(float4*)&out[((size_t)(b * TOUT + t)) * NCH + ng * 4] = v;
    }
}

extern "C" void kernel_launch(void* const* d_in, const int* in_sizes, int n_in,
                              void* d_out, int out_size, void* d_ws, size_t ws_size,
                              hipStream_t stream)
{
    const float* X  = (const float*)d_in[0];
    const float* W0 = (const float*)d_in[1];
    const float* b0 = (const float*)d_in[2];
    const float* W1 = (const float*)d_in[3];
    const float* b1 = (const float*)d_in[4];
    const float* W2 = (const float*)d_in[5];
    const float* b2 = (const float*)d_in[6];
    float* out = (float*)d_out;

    unsigned short* W0b = (unsigned short*)d_ws;                    // 1,310,720 B
    unsigned short* W1b = (unsigned short*)((char*)d_ws + 1310720); //   131,072 B
    unsigned short* W2b = (unsigned short*)((char*)d_ws + 1441792); //     4,096 B

    prep_w<<<545, 256, 0, stream>>>(W0, W0b, W1, W1b, W2, W2b);
    mlp_mfma<<<dim3(128, 16), 256, 0, stream>>>(X, W0b, W1b, W2b, b0, b1, b2, out);
}